// Round 19
// baseline (108.320 us; speedup 1.0000x reference)
//
#include <hip/hip_runtime.h>
#include <math.h>

#define CAPV 0.99f

// ---------------------------------------------------------------------------
// Kernel 1: per-batch angle/diag precompute, 4 lanes per output + shfl reduce.
// cs layout per batch (1024 float2):
//   [0,512):    stages 1-4, natural pair order.
//   [512,1024): stages 5-8 reordered by (c0=c&15, q) (pass-2 friendly).
// diag2 transposed: diag2[b*256 + (c&15)*16 + (c>>4)].
// ---------------------------------------------------------------------------
__global__ void pr_precompute(const float* __restrict__ mod,
                              const float* __restrict__ angles,
                              const float* __restrict__ diagonal,
                              const float* __restrict__ w_angle,
                              const float* __restrict__ w_diag,
                              float2* __restrict__ cs,
                              float* __restrict__ diag2) {
    const int gid = blockIdx.x * blockDim.x + threadIdx.x;  // 0..163839
    const int o = gid >> 2;                                  // output id
    const int r = gid & 3;                                   // reduce lane

    if (o < 32768) {                       // ---- cos/sin outputs ----
        const int b = o >> 10;
        const int p = o & 1023;
        const float4* m = (const float4*)(mod + (size_t)b * 256);
        const float4* w = (const float4*)(w_angle + (size_t)p * 256);
        float acc = 0.f;
#pragma unroll
        for (int i = 0; i < 16; ++i) {
            const float4 a = m[i * 4 + r];
            const float4 c = w[i * 4 + r];
            acc += a.x * c.x + a.y * c.y + a.z * c.z + a.w * c.w;
        }
        acc += __shfl_xor(acc, 1, 64);
        acc += __shfl_xor(acc, 2, 64);
        if (r == 0) {
            const float ang = angles[p] + tanhf(acc);
            float sv, cv;
            sincosf(ang, &sv, &cv);
            int outp;
            if (p < 512) {
                outp = p;
            } else {
                const int st   = (p >> 7) + 1;        // 5..8
                const int lp   = p & 127;
                const int half = 1 << (st - 1);
                const int c    = ((lp >> (st - 1)) << st) | (lp & (half - 1));
                const int k    = c >> 4;
                const int c0   = c & 15;
                int q;
                if (st == 5)      q = k >> 1;
                else if (st == 6) q = (k >> 2) * 2 + (k & 1);
                else if (st == 7) q = (k >> 3) * 4 + (k & 3);
                else              q = k;
                outp = 512 + (st - 5) * 128 + c0 * 8 + q;
            }
            cs[(size_t)b * 1024 + outp] = make_float2(cv, sv);
        }
    } else {                               // ---- diag outputs ----
        const int o2 = o - 32768;          // 0..8191
        const int b2 = o2 >> 8;
        const int cd = o2 & 255;
        const float4* m = (const float4*)(mod + (size_t)b2 * 256);
        const float4* w = (const float4*)(w_diag + (size_t)cd * 256);
        float acc = 0.f;
#pragma unroll
        for (int i = 0; i < 16; ++i) {
            const float4 a = m[i * 4 + r];
            const float4 c = w[i * 4 + r];
            acc += a.x * c.x + a.y * c.y + a.z * c.z + a.w * c.w;
        }
        acc += __shfl_xor(acc, 1, 64);
        acc += __shfl_xor(acc, 2, 64);
        if (r == 0) {
            float bd = tanhf(diagonal[cd]);
            bd = fminf(fmaxf(bd, -CAPV), CAPV);
            float d = bd + tanhf(acc);
            d = fminf(fmaxf(d, -CAPV), CAPV);
            diag2[(size_t)b2 * 256 + (cd & 15) * 16 + (cd >> 4)] = d;
        }
    }
}

// ---------------------------------------------------------------------------
// Kernel 2a: stages 1-4, pure streaming, no LDS/barriers, HIGH OCCUPANCY.
// r18 -> r19: thread = 16 contiguous channels x 2 points (float2 y[16] = 32
// data VGPRs; __launch_bounds__(256,8) caps at 64 VGPR -> 32 waves/CU; r18's
// float4 version was 68 VGPR -> 16 waves/CU cap, measured 24%).
// Grid 4096: b = blk>>7, g = (blk>>3)&15, win = blk&7 (512-pt windows).
// Per row: wave reads/writes 512 B, block 2 KB contiguous -> clean write
// stream (r18 measured WRITE exactly ideal, 131072 KB).
// cs reads are block-uniform -> scalar loads. x -> out (temp for pass 2).
// ---------------------------------------------------------------------------
__global__ __launch_bounds__(256, 8)
void pr_pass1(const float* __restrict__ x, const float2* __restrict__ cs,
              float* __restrict__ out) {
    const int blk = blockIdx.x;           // 4096
    const int b   = blk >> 7;
    const int g   = (blk >> 3) & 15;
    const int win = blk & 7;
    const size_t base = (size_t)b * 1048576 + (size_t)(g * 16) * 4096
                      + (size_t)win * 512 + (size_t)threadIdx.x * 2;
    const float* __restrict__ xb = x + base;
    float* __restrict__ ob = out + base;
    const float2* __restrict__ csb = cs + (size_t)b * 1024;

    float2 y[16];
#pragma unroll
    for (int j = 0; j < 16; ++j)
        y[j] = *(const float2*)(xb + (size_t)j * 4096);

#pragma unroll
    for (int st = 1; st <= 4; ++st) {
        const int h = 1 << (st - 1);
        const float4* c4 = (const float4*)(csb + ((st - 1) * 128 + g * 8));
        float4 cq[4];
#pragma unroll
        for (int i = 0; i < 4; ++i) cq[i] = c4[i];
#pragma unroll
        for (int q = 0; q < 8; ++q) {
            const int jl = ((q >> (st - 1)) << st) | (q & (h - 1));
            const int jr = jl | h;
            const float cc = (q & 1) ? cq[q >> 1].z : cq[q >> 1].x;
            const float ss = (q & 1) ? cq[q >> 1].w : cq[q >> 1].y;
            const float2 l = y[jl];
            const float2 r = y[jr];
            y[jl].x = fmaf(cc, l.x, ss * r.x);
            y[jl].y = fmaf(cc, l.y, ss * r.y);
            y[jr].x = fmaf(cc, r.x, -(ss * l.x));
            y[jr].y = fmaf(cc, r.y, -(ss * l.y));
        }
    }

#pragma unroll
    for (int j = 0; j < 16; ++j)
        *(float2*)(ob + (size_t)j * 4096) = y[j];
}

// ---------------------------------------------------------------------------
// Kernel 2b: stages 5-8 + diagonal, in-place on out, HIGH OCCUPANCY.
// Thread = 16 stride-16 channels (c = g + 16k) x 2 points. Stage-5..8
// pairs inside the set (partner k + 2^(st-5)). cs region-2 (reordered)
// gives contiguous coefficients; diag2 transposed gives 16 contiguous
// floats per (b,g). Reads out (pass-1 temp, largely cache-resident),
// rewrites the same addresses (one owner per address; stream-order safe).
// ---------------------------------------------------------------------------
__global__ __launch_bounds__(256, 8)
void pr_pass2(const float2* __restrict__ cs, const float* __restrict__ diag2,
              float* __restrict__ out) {
    const int blk = blockIdx.x;           // 4096
    const int b   = blk >> 7;
    const int g   = (blk >> 3) & 15;
    const int win = blk & 7;
    const size_t base = (size_t)b * 1048576 + (size_t)g * 4096
                      + (size_t)win * 512 + (size_t)threadIdx.x * 2;
    float* __restrict__ ob = out + base;
    const float2* __restrict__ csb = cs + (size_t)b * 1024;

    float2 z[16];
#pragma unroll
    for (int k = 0; k < 16; ++k)
        z[k] = *(const float2*)(ob + (size_t)k * 65536);

#pragma unroll
    for (int st = 5; st <= 8; ++st) {
        const int sb = st - 5;
        const float4* c4 = (const float4*)csb + 256 + sb * 64 + g * 4;
        float4 cq[4];
#pragma unroll
        for (int i = 0; i < 4; ++i) cq[i] = c4[i];
#pragma unroll
        for (int q = 0; q < 8; ++q) {
            int k;
            if (st == 5)      k = q * 2;
            else if (st == 6) k = (q >> 1) * 4 + (q & 1);
            else if (st == 7) k = (q >> 2) * 8 + (q & 3);
            else              k = q;
            const int k2 = k + (1 << sb);
            const float cc = (q & 1) ? cq[q >> 1].z : cq[q >> 1].x;
            const float ss = (q & 1) ? cq[q >> 1].w : cq[q >> 1].y;
            const float2 l = z[k];
            const float2 r = z[k2];
            z[k].x  = fmaf(cc, l.x, ss * r.x);
            z[k].y  = fmaf(cc, l.y, ss * r.y);
            z[k2].x = fmaf(cc, r.x, -(ss * l.x));
            z[k2].y = fmaf(cc, r.y, -(ss * l.y));
        }
    }

    // Diagonal: diag2[b*256 + g*16 + k] (c = g+16k -> (c&15)=g, (c>>4)=k).
    {
        const float4* d4 = (const float4*)(diag2 + (size_t)b * 256 + g * 16);
#pragma unroll
        for (int i = 0; i < 4; ++i) {
            const float4 dv = d4[i];
#pragma unroll
            for (int j = 0; j < 4; ++j) {
                const float dj = (j == 0) ? dv.x : (j == 1) ? dv.y
                               : (j == 2) ? dv.z : dv.w;
                z[i * 4 + j].x *= dj;
                z[i * 4 + j].y *= dj;
            }
        }
    }

#pragma unroll
    for (int k = 0; k < 16; ++k)
        *(float2*)(ob + (size_t)k * 65536) = z[k];
}

// ---------------------------------------------------------------------------
extern "C" void kernel_launch(void* const* d_in, const int* in_sizes, int n_in,
                              void* d_out, int out_size, void* d_ws, size_t ws_size,
                              hipStream_t stream) {
    const float* x        = (const float*)d_in[0];  // (32,256,64,64)
    const float* mod      = (const float*)d_in[1];  // (32,256)
    const float* angles   = (const float*)d_in[2];  // (1024,)
    const float* diagonal = (const float*)d_in[3];  // (256,)
    const float* w_angle  = (const float*)d_in[4];  // (1024,256)
    const float* w_diag   = (const float*)d_in[5];  // (256,256)
    float* out = (float*)d_out;

    float2* cs    = (float2*)d_ws;                                      // 256 KB
    float*  diag2 = (float*)((char*)d_ws + 32 * 1024 * sizeof(float2)); // 32 KB

    pr_precompute<<<640, 256, 0, stream>>>(mod, angles, diagonal, w_angle, w_diag, cs, diag2);
    pr_pass1<<<4096, 256, 0, stream>>>(x, cs, out);
    pr_pass2<<<4096, 256, 0, stream>>>(cs, diag2, out);
}

// Round 20
// 83.893 us; speedup vs baseline: 1.2912x; 1.2912x over previous
//
#include <hip/hip_runtime.h>
#include <math.h>

#define CAPV 0.99f

// Raw lgkm-only barrier (does NOT drain vmcnt): prefetch loads and stores
// stay in flight across it (r11: draining barriers = mega-burst regression).
#define WG_BARRIER() do {                                   \
    asm volatile("s_waitcnt lgkmcnt(0)" ::: "memory");      \
    __builtin_amdgcn_s_barrier();                           \
    asm volatile("" ::: "memory");                          \
} while (0)

// ---------------------------------------------------------------------------
// Kernel 1: per-batch angle/diag precompute, 4 lanes per output + shfl reduce.
// cs layout per batch (1024 float2):
//   [0,512):    stages 1-4, natural pair order.
//   [512,1024): stages 5-8 reordered by (c0=c&15, q) (pass-2 friendly).
// diag2 transposed: diag2[b*256 + (c&15)*16 + (c>>4)].
// ---------------------------------------------------------------------------
__global__ void pr_precompute(const float* __restrict__ mod,
                              const float* __restrict__ angles,
                              const float* __restrict__ diagonal,
                              const float* __restrict__ w_angle,
                              const float* __restrict__ w_diag,
                              float2* __restrict__ cs,
                              float* __restrict__ diag2) {
    const int gid = blockIdx.x * blockDim.x + threadIdx.x;  // 0..163839
    const int o = gid >> 2;                                  // output id
    const int r = gid & 3;                                   // reduce lane

    if (o < 32768) {                       // ---- cos/sin outputs ----
        const int b = o >> 10;
        const int p = o & 1023;
        const float4* m = (const float4*)(mod + (size_t)b * 256);
        const float4* w = (const float4*)(w_angle + (size_t)p * 256);
        float acc = 0.f;
#pragma unroll
        for (int i = 0; i < 16; ++i) {
            const float4 a = m[i * 4 + r];
            const float4 c = w[i * 4 + r];
            acc += a.x * c.x + a.y * c.y + a.z * c.z + a.w * c.w;
        }
        acc += __shfl_xor(acc, 1, 64);
        acc += __shfl_xor(acc, 2, 64);
        if (r == 0) {
            const float ang = angles[p] + tanhf(acc);
            float sv, cv;
            sincosf(ang, &sv, &cv);
            int outp;
            if (p < 512) {
                outp = p;
            } else {
                const int st   = (p >> 7) + 1;        // 5..8
                const int lp   = p & 127;
                const int half = 1 << (st - 1);
                const int c    = ((lp >> (st - 1)) << st) | (lp & (half - 1));
                const int k    = c >> 4;
                const int c0   = c & 15;
                int q;
                if (st == 5)      q = k >> 1;
                else if (st == 6) q = (k >> 2) * 2 + (k & 1);
                else if (st == 7) q = (k >> 3) * 4 + (k & 3);
                else              q = k;
                outp = 512 + (st - 5) * 128 + c0 * 8 + q;
            }
            cs[(size_t)b * 1024 + outp] = make_float2(cv, sv);
        }
    } else {                               // ---- diag outputs ----
        const int o2 = o - 32768;          // 0..8191
        const int b2 = o2 >> 8;
        const int cd = o2 & 255;
        const float4* m = (const float4*)(mod + (size_t)b2 * 256);
        const float4* w = (const float4*)(w_diag + (size_t)cd * 256);
        float acc = 0.f;
#pragma unroll
        for (int i = 0; i < 16; ++i) {
            const float4 a = m[i * 4 + r];
            const float4 c = w[i * 4 + r];
            acc += a.x * c.x + a.y * c.y + a.z * c.z + a.w * c.w;
        }
        acc += __shfl_xor(acc, 1, 64);
        acc += __shfl_xor(acc, 2, 64);
        if (r == 0) {
            float bd = tanhf(diagonal[cd]);
            bd = fminf(fmaxf(bd, -CAPV), CAPV);
            float d = bd + tanhf(acc);
            d = fminf(fmaxf(d, -CAPV), CAPV);
            diag2[(size_t)b2 * 256 + (cd & 15) * 16 + (cd >> 4)] = d;
        }
    }
}

// ---------------------------------------------------------------------------
// Kernel 2: pipelined two-pass butterfly (r13 configuration — session best,
// 83.9 us). Block = 512 thr (8 waves), tile = 256 ch x 64 pts = 64 KB LDS,
// 2 blocks/CU (16 waves/CU), grid 512, 4 windows/block.
//
// widx = blk & 63 (FIXED spatial window), b = (blk>>6)*4 + t: batch-major
// walk — a block never writes two temporally-separated chunks of the same
// row region; adjacent 256-B chunks of a row belong to adjacent co-resident
// blocks (cut WRITE 255 -> 184 MB vs multi-window-same-row walks).
//
// Plain float4 stores: nt amplified writes ~1.9x in every layout (r6-r12);
// sc1 broke correctness vs the harness's cached poison lines (r17).
// Raw non-draining barriers (r11: draining = phase-locked mega-bursts).
// Depth-2 register prefetch (rfA/rfB, statically unrolled t-loop).
//
// LDS swizzle (16B slots): phys = slot ^ (((row^(row>>4))&3)<<1).
// Measured SQ_LDS_BANK_CONFLICT = 0 (r13).
//
// Residual vs 41-us ideal floor: ~1.44x write-granule amplification +
// mixed-stream efficiency ~55% — both survived every source-level
// countermeasure tried (store flavors, chunk sizes 128/256/512B, XCD
// grouping, adjacency, occupancy 2x/4x, draining/non-draining barriers,
// two-pass streaming). This is the empirical optimum of the space.
// ---------------------------------------------------------------------------
__global__ __launch_bounds__(512, 4)
void pr_butterfly(const float* __restrict__ x,
                  const float2* __restrict__ cs,
                  const float* __restrict__ diag2,
                  float* __restrict__ out) {
    __shared__ __align__(16) float tile[256 * 64];   // 64 KB

    const int tid  = threadIdx.x;
    const int blk  = blockIdx.x;          // 512 blocks
    const int widx = blk & 63;            // fixed spatial window 0..63
    const int bg   = blk >> 6;            // batch group 0..7

    const int lane = tid & 63;
    const int wv   = tid >> 6;            // 0..7
    const int rr   = tid >> 4;            // staging row-in-group 0..31
    const int sl   = tid & 15;            // staging 16B slot 0..15
    const int A    = lane >> 2;           // channel group 0..15
    const int pq   = lane & 3;
    const int p    = wv * 8 + pq * 2;     // this thread's 2 points (0..63)
    const int pl   = p & 3;
    const int ps   = p >> 2;              // logical 16B slot of the points

    const int ptB = widx * 64;            // constant across windows

    float4 rfA[8], rfB[8];

    // Prologue: prefetch windows 0 and 1 (batches bg*4, bg*4+1).
    {
        const float* xb0 = x + (size_t)(bg * 4) * 1048576;
        const float* xb1 = xb0 + 1048576;
#pragma unroll
        for (int it = 0; it < 8; ++it) {
            const int row = it * 32 + rr;
            rfA[it] = *(const float4*)(xb0 + (size_t)row * 4096 + ptB + sl * 4);
        }
#pragma unroll
        for (int it = 0; it < 8; ++it) {
            const int row = it * 32 + rr;
            rfB[it] = *(const float4*)(xb1 + (size_t)row * 4096 + ptB + sl * 4);
        }
    }

#pragma unroll
    for (int t = 0; t < 4; ++t) {
        const int b = bg * 4 + t;
        float* __restrict__ ob = out + (size_t)b * 1048576;
        const float2* __restrict__ csb = cs + (size_t)b * 1024;

        // (a) regs -> LDS, own rows, swizzled slots. t is compile-time
        //     (full unroll) -> buffer choice is static (no scratch).
#pragma unroll
        for (int it = 0; it < 8; ++it) {
            const int row = it * 32 + rr;
            const int swz = ((row ^ (row >> 4)) & 3) << 1;
            const float4 v = (t & 1) ? rfB[it] : rfA[it];
            *(float4*)&tile[row * 64 + ((sl ^ swz) << 2)] = v;
        }

        // (b) refill the just-consumed buffer with window t+2 (batch b+2).
        if (t < 2) {
            const float* xbn = x + (size_t)(b + 2) * 1048576;
#pragma unroll
            for (int it = 0; it < 8; ++it) {
                const int row = it * 32 + rr;
                const float4 v = *(const float4*)(xbn + (size_t)row * 4096 + ptB + sl * 4);
                if (t & 1) rfB[it] = v; else rfA[it] = v;
            }
        }

        // (c) all waves' rows staged.
        WG_BARRIER();

        // ---- pass 1: 16 contiguous channels (c = A*16+j), stages 1..4 ----
        {
            float2 y[16];
#pragma unroll
            for (int j = 0; j < 16; ++j) {
                const int swz = ((j ^ A) & 3) << 1;
                y[j] = *(const float2*)&tile[(A * 16 + j) * 64 + ((ps ^ swz) << 2) + pl];
            }

#pragma unroll
            for (int st = 1; st <= 4; ++st) {
                const int h = 1 << (st - 1);
                const float4* c4 = (const float4*)(csb + ((st - 1) * 128 + A * 8));
                float4 cq[4];
#pragma unroll
                for (int i = 0; i < 4; ++i) cq[i] = c4[i];
#pragma unroll
                for (int q = 0; q < 8; ++q) {
                    const int jl = ((q >> (st - 1)) << st) | (q & (h - 1));
                    const int jr = jl | h;
                    const float cc = (q & 1) ? cq[q >> 1].z : cq[q >> 1].x;
                    const float ss = (q & 1) ? cq[q >> 1].w : cq[q >> 1].y;
                    const float2 l = y[jl];
                    const float2 r = y[jr];
                    y[jl].x = fmaf(cc, l.x, ss * r.x);
                    y[jl].y = fmaf(cc, l.y, ss * r.y);
                    y[jr].x = fmaf(cc, r.x, -(ss * l.x));
                    y[jr].y = fmaf(cc, r.y, -(ss * l.y));
                }
            }

#pragma unroll
            for (int j = 0; j < 16; ++j) {
                const int swz = ((j ^ A) & 3) << 1;
                *(float2*)&tile[(A * 16 + j) * 64 + ((ps ^ swz) << 2) + pl] = y[j];
            }
        }

        // (e) pass1 -> pass2 exchange is intra-wave only: LDS fence suffices.
        asm volatile("s_waitcnt lgkmcnt(0)" ::: "memory");

        // ---- pass 2: 16 stride-16 channels (c = A + 16k), stages 5..8 ----
        {
            float2 z[16];
#pragma unroll
            for (int k = 0; k < 16; ++k) {
                const int swz = ((A ^ k) & 3) << 1;
                z[k] = *(const float2*)&tile[(A + k * 16) * 64 + ((ps ^ swz) << 2) + pl];
            }

#pragma unroll
            for (int st = 5; st <= 8; ++st) {
                const int sb = st - 5;
                const float4* c4 = (const float4*)csb + 256 + sb * 64 + A * 4;
                float4 cq[4];
#pragma unroll
                for (int i = 0; i < 4; ++i) cq[i] = c4[i];
#pragma unroll
                for (int q = 0; q < 8; ++q) {
                    int k;
                    if (st == 5)      k = q * 2;
                    else if (st == 6) k = (q >> 1) * 4 + (q & 1);
                    else if (st == 7) k = (q >> 2) * 8 + (q & 3);
                    else              k = q;
                    const int k2 = k + (1 << sb);
                    const float cc = (q & 1) ? cq[q >> 1].z : cq[q >> 1].x;
                    const float ss = (q & 1) ? cq[q >> 1].w : cq[q >> 1].y;
                    const float2 l = z[k];
                    const float2 r = z[k2];
                    z[k].x  = fmaf(cc, l.x, ss * r.x);
                    z[k].y  = fmaf(cc, l.y, ss * r.y);
                    z[k2].x = fmaf(cc, r.x, -(ss * l.x));
                    z[k2].y = fmaf(cc, r.y, -(ss * l.y));
                }
            }

            // Diagonal (transposed: 16 contiguous floats for this thread).
            {
                const float4* d4 = (const float4*)(diag2 + (size_t)b * 256 + A * 16);
#pragma unroll
                for (int i = 0; i < 4; ++i) {
                    const float4 dv = d4[i];
                    z[i * 4 + 0].x *= dv.x;  z[i * 4 + 0].y *= dv.x;
                    z[i * 4 + 1].x *= dv.y;  z[i * 4 + 1].y *= dv.y;
                    z[i * 4 + 2].x *= dv.z;  z[i * 4 + 2].y *= dv.z;
                    z[i * 4 + 3].x *= dv.w;  z[i * 4 + 3].y *= dv.w;
                }
            }

#pragma unroll
            for (int k = 0; k < 16; ++k) {
                const int swz = ((A ^ k) & 3) << 1;
                *(float2*)&tile[(A + k * 16) * 64 + ((ps ^ swz) << 2) + pl] = z[k];
            }
        }

        // (g) all waves' pass-2 writes visible; prefetch loads stay in flight.
        WG_BARRIER();

        // (h) store own rows: swizzled LDS read, plain 256-B store per row;
        //     adjacent row chunks stored by adjacent co-resident blocks.
#pragma unroll
        for (int it = 0; it < 8; ++it) {
            const int row = it * 32 + rr;
            const int swz = ((row ^ (row >> 4)) & 3) << 1;
            const float4 v = *(const float4*)&tile[row * 64 + ((sl ^ swz) << 2)];
            *(float4*)(ob + (size_t)row * 4096 + ptB + sl * 4) = v;
        }
    }
}

// ---------------------------------------------------------------------------
extern "C" void kernel_launch(void* const* d_in, const int* in_sizes, int n_in,
                              void* d_out, int out_size, void* d_ws, size_t ws_size,
                              hipStream_t stream) {
    const float* x        = (const float*)d_in[0];  // (32,256,64,64)
    const float* mod      = (const float*)d_in[1];  // (32,256)
    const float* angles   = (const float*)d_in[2];  // (1024,)
    const float* diagonal = (const float*)d_in[3];  // (256,)
    const float* w_angle  = (const float*)d_in[4];  // (1024,256)
    const float* w_diag   = (const float*)d_in[5];  // (256,256)
    float* out = (float*)d_out;

    float2* cs    = (float2*)d_ws;                                      // 256 KB
    float*  diag2 = (float*)((char*)d_ws + 32 * 1024 * sizeof(float2)); // 32 KB

    pr_precompute<<<640, 256, 0, stream>>>(mod, angles, diagonal, w_angle, w_diag, cs, diag2);
    pr_butterfly<<<512, 512, 0, stream>>>(x, cs, diag2, out);
}